// Round 5
// baseline (23483.444 us; speedup 1.0000x reference)
//
#include <hip/hip_runtime.h>
#include <hip/hip_bf16.h>
#include <cstdint>
#include <cstddef>

#define N_NODES 50000
#define N_EDGES 200000
#define N_GRAPH 2048
#define DD 256
#define HH 512
#define LL 12
#define NODE_IN_F 173
#define EDGE_IN_F 13

typedef __hip_bfloat16 bf16;
typedef __attribute__((ext_vector_type(8))) short short8;
typedef __attribute__((ext_vector_type(4))) float f32x4;
typedef __attribute__((ext_vector_type(4))) unsigned short us4;

__device__ __forceinline__ float bfbits2f(unsigned short u) {
    return __uint_as_float(((unsigned)u) << 16);
}
__device__ __forceinline__ unsigned short f2bfbits(float f) {
    bf16 h = __float2bfloat16(f);
    return __builtin_bit_cast(unsigned short, h);
}

// async global->LDS 16B per lane; LDS dest = wave-uniform base + lane*16
__device__ __forceinline__ void gld16(const void* g, void* l) {
    __builtin_amdgcn_global_load_lds(
        (const __attribute__((address_space(1))) unsigned int*)g,
        (__attribute__((address_space(3))) unsigned int*)l, 16, 0, 0);
}

// ---------------------------------------------------------------------------
// MFMA multi-part gather GEMM with hi/lo-split bf16 weights.
//   C[M,N] = act( sum_p A_p[idx_p? idx_p[r]:r, :Kp] @ (Whi_p + Wlo_p)^T + bias ) (+res)
//
// 256x128 tile, 512 threads (8 waves: 4 row-waves x 2 col-waves, 64x64 each).
// QUAD-buffered LDS (128 KB), depth-3 prefetch, counted s_waitcnt vmcnt(8/4/0)
// + raw s_barrier. 4 gld16 per wave per stage, deterministic count (A rows
// clamped at M). Gather indices are K-independent -> preloaded to registers
// (pa0..pa3) so the stage path has NO vmem loads and the counted-vmcnt
// pipeline never drains (the R4 version re-loaded idx[] per stage, which
// forced an in-order vmcnt drain inside every gather stage).
// Epilogue: per-wave LDS transpose (stride 68 f32) -> 2x16B coalesced stores.
// ---------------------------------------------------------------------------
#define TBM 256
#define TBN 128

struct GMArgs {
    const bf16* A[4];
    const int*  idx[4];
    const bf16* whi[4];
    const bf16* wlo[4];
    int lda[4];
    int ldw[4];
    int Kp[4];
    int nparts;
    int M, N;            // ldc == N
    const float* bias;
    const bf16* res;     // row stride N
    bf16* C;
    int relu;
};

__global__ __launch_bounds__(512)
void gemm_mfma(GMArgs g)
{
    __shared__ __align__(16) short AsL[4 * TBM * 32];   // 64 KB
    __shared__ __align__(16) short BhL[4 * TBN * 32];   // 32 KB
    __shared__ __align__(16) short BlL[4 * TBN * 32];   // 32 KB

    const int tid  = threadIdx.x;
    const int lane = tid & 63;
    const int wv   = tid >> 6;          // 0..7
    const int wm   = (wv >> 1) * 64;    // wave row offset: 0/64/128/192
    const int wn   = (wv & 1) * 64;     // wave col offset: 0/64
    const int quad = lane >> 4;
    const int l16  = lane & 15;
    const int rq   = lane >> 2;         // staging: row-within-slab 0..15
    const int qq   = lane & 3;          // staging: 16B quarter 0..3

    // XCD-aware bijective swizzle (m204)
    const int gx  = gridDim.x;
    const int nwg = gx * gridDim.y;
    int hw  = blockIdx.y * gx + blockIdx.x;
    int xcd = hw & 7, rk = hw >> 3;
    int q = nwg >> 3, r = nwg & 7;
    int lid = (xcd < r ? xcd * (q + 1) : r * (q + 1) + (xcd - r) * q) + rk;
    const int row0 = (lid / gx) * TBM;
    const int col0 = (lid % gx) * TBN;

    // flatten (part, k-step) into step index t = 0..T-1
    int steps[4]; int T = 0;
#pragma unroll
    for (int p = 0; p < 4; ++p) { steps[p] = (p < g.nparts) ? (g.Kp[p] >> 5) : 0; T += steps[p]; }

    // preload K-independent gather row indices (waves 0..3 own the A slabs)
    int pa0[4], pa1[4], pa2[4], pa3[4];
#pragma unroll
    for (int s = 0; s < 4; ++s) {
        int sid = wv * 4 + s;
        int r2 = (sid & 15) * 16 + rq;
        int grr = row0 + r2;
        int cr = grr < g.M ? grr : g.M - 1;   // clamp: deterministic load count
        pa0[s] = (g.nparts > 0 && g.idx[0]) ? g.idx[0][cr] : cr;
        pa1[s] = (g.nparts > 1 && g.idx[1]) ? g.idx[1][cr] : cr;
        pa2[s] = (g.nparts > 2 && g.idx[2]) ? g.idx[2][cr] : cr;
        pa3[s] = (g.nparts > 3 && g.idx[3]) ? g.idx[3][cr] : cr;
    }

    f32x4 acc[4][4];
#pragma unroll
    for (int i = 0; i < 4; ++i)
#pragma unroll
        for (int j = 0; j < 4; ++j)
            acc[i][j] = (f32x4){0.f, 0.f, 0.f, 0.f};

    // 32 slabs/stage: sid 0..15 = A rows sid*16; 16..23 = Bh; 24..31 = Bl.
    // wave wv handles sid = wv*4 + s  (wave-uniform branches, 4 gld16/wave)
    auto stage = [&](int t, int b) {
        int p = 0, tt = t;
        while (tt >= steps[p]) { tt -= steps[p]; ++p; }
        const int k0 = tt << 5;
        const short* Ap  = (const short*)g.A[p];
        const short* Whi = (const short*)g.whi[p];
        const short* Wlo = (const short*)g.wlo[p];
        const int lda = g.lda[p];
        const int ldw = g.ldw[p];
        const int kcol = k0 + qq * 8;
#pragma unroll
        for (int s = 0; s < 4; ++s) {
            const int sid = wv * 4 + s;
            if (sid < 16) {
                int ar = (p == 0) ? pa0[s] : (p == 1) ? pa1[s] : (p == 2) ? pa2[s] : pa3[s];
                gld16(Ap + (size_t)ar * lda + kcol,
                      AsL + (size_t)b * (TBM * 32) + sid * (16 * 32));
            } else if (sid < 24) {
                int r2 = (sid - 16) * 16 + rq;
                gld16(Whi + (size_t)(col0 + r2) * ldw + kcol,
                      BhL + (size_t)b * (TBN * 32) + (sid - 16) * (16 * 32));
            } else {
                int r2 = (sid - 24) * 16 + rq;
                gld16(Wlo + (size_t)(col0 + r2) * ldw + kcol,
                      BlL + (size_t)b * (TBN * 32) + (sid - 24) * (16 * 32));
            }
        }
    };

    stage(0, 0);
    if (T > 1) stage(1, 1);
    if (T > 2) stage(2, 2);
    for (int t = 0; t < T; ++t) {
        // certify stage-t landed; keep up to 2 newer stages (8 loads) in flight
        if (t + 2 < T)      asm volatile("s_waitcnt vmcnt(8)" ::: "memory");
        else if (t + 1 < T) asm volatile("s_waitcnt vmcnt(4)" ::: "memory");
        else                asm volatile("s_waitcnt vmcnt(0)" ::: "memory");
        __builtin_amdgcn_s_barrier();   // stage-t visible to all; buf (t+3)&3 free
        asm volatile("" ::: "memory");
        if (t + 3 < T) stage(t + 3, (t + 3) & 3);

        const int cur = t & 3;
        const short* Ab = AsL + (size_t)cur * (TBM * 32);
        const short* Bhb = BhL + (size_t)cur * (TBN * 32);
        const short* Blb = BlL + (size_t)cur * (TBN * 32);
        short8 a[4], bh[4], bl[4];
#pragma unroll
        for (int i = 0; i < 4; ++i)
            a[i] = *(const short8*)&Ab[(wm + i * 16 + l16) * 32 + quad * 8];
#pragma unroll
        for (int j = 0; j < 4; ++j) {
            bh[j] = *(const short8*)&Bhb[(wn + j * 16 + l16) * 32 + quad * 8];
            bl[j] = *(const short8*)&Blb[(wn + j * 16 + l16) * 32 + quad * 8];
        }
#pragma unroll
        for (int i = 0; i < 4; ++i)
#pragma unroll
            for (int j = 0; j < 4; ++j)
                acc[i][j] = __builtin_amdgcn_mfma_f32_16x16x32_bf16(a[i], bh[j], acc[i][j], 0, 0, 0);
#pragma unroll
        for (int i = 0; i < 4; ++i)
#pragma unroll
            for (int j = 0; j < 4; ++j)
                acc[i][j] = __builtin_amdgcn_mfma_f32_16x16x32_bf16(a[i], bl[j], acc[i][j], 0, 0, 0);
    }

    // ---- epilogue: per-wave LDS transpose -> coalesced 16B stores ----
    __syncthreads();   // all LDS reads done; reuse AsL as scratch (35 KB used)
    {
        const int SROW = 68;                                  // padded f32 stride
        float* Sw = (float*)AsL + wv * (16 * SROW);           // per-wave [16][68]
        const int erow = lane >> 2;                           // 0..15
        const int ecb  = lane & 3;                            // 16-col block
        float bc[4];
#pragma unroll
        for (int j = 0; j < 4; ++j)
            bc[j] = g.bias ? g.bias[col0 + wn + j * 16 + l16] : 0.f;
        const int grb = row0 + wm;
#pragma unroll
        for (int i = 0; i < 4; ++i) {
#pragma unroll
            for (int j = 0; j < 4; ++j)
#pragma unroll
                for (int r3 = 0; r3 < 4; ++r3) {
                    float v = acc[i][j][r3] + bc[j];
                    if (g.relu) v = fmaxf(v, 0.f);
                    Sw[(quad * 4 + r3) * SROW + j * 16 + l16] = v;
                }
            int gr = grb + i * 16 + erow;
            if (gr < g.M) {
                const float* sr = Sw + erow * SROW + ecb * 16;
                f32x4 q0 = *(const f32x4*)(sr + 0);
                f32x4 q1 = *(const f32x4*)(sr + 4);
                f32x4 q2 = *(const f32x4*)(sr + 8);
                f32x4 q3 = *(const f32x4*)(sr + 12);
                size_t ob = (size_t)gr * g.N + col0 + wn + ecb * 16;
                float v[16];
                *(f32x4*)&v[0] = q0; *(f32x4*)&v[4] = q1;
                *(f32x4*)&v[8] = q2; *(f32x4*)&v[12] = q3;
                if (g.res) {
                    const short* rp = (const short*)g.res + ob;
                    short8 r0 = *(const short8*)rp;
                    short8 r1 = *(const short8*)(rp + 8);
#pragma unroll
                    for (int k = 0; k < 8; ++k) {
                        v[k]     += bfbits2f((unsigned short)r0[k]);
                        v[8 + k] += bfbits2f((unsigned short)r1[k]);
                    }
                }
                short8 o0, o1;
#pragma unroll
                for (int k = 0; k < 8; ++k) {
                    o0[k] = (short)f2bfbits(v[k]);
                    o1[k] = (short)f2bfbits(v[8 + k]);
                }
                short* cp = (short*)g.C + ob;
                *(short8*)cp = o0;
                *(short8*)(cp + 8) = o1;
            }
        }
    }
}

// host-side builders
static inline GMArgs gm_new(int M, int N) {
    GMArgs g;
    for (int i = 0; i < 4; ++i) { g.A[i] = nullptr; g.idx[i] = nullptr; g.whi[i] = nullptr; g.wlo[i] = nullptr; g.lda[i] = 0; g.ldw[i] = 0; g.Kp[i] = 0; }
    g.nparts = 0; g.M = M; g.N = N; g.bias = nullptr; g.res = nullptr; g.C = nullptr; g.relu = 0;
    return g;
}
static inline void gm_part(GMArgs& g, const bf16* A, int lda, const int* idx,
                           const bf16* whi, const bf16* wlo, int ldw, int Kp) {
    int p = g.nparts++;
    g.A[p] = A; g.lda[p] = lda; g.idx[p] = idx; g.whi[p] = whi; g.wlo[p] = wlo; g.ldw[p] = ldw; g.Kp[p] = Kp;
}
static inline void gm_run(hipStream_t s, GMArgs& g, const float* bias,
                          const bf16* res, bf16* C, int relu) {
    g.bias = bias; g.res = res; g.C = C; g.relu = relu;
    dim3 grid(g.N / TBN, (g.M + TBM - 1) / TBM);
    gemm_mfma<<<grid, dim3(512), 0, s>>>(g);
}

// ---------------------------------------------------------------------------
// batched weight convert: W fp32 [K][N] -> Whi/Wlo bf16 [N][Kp] (transposed, padded)
// ---------------------------------------------------------------------------
struct ConvDesc { const float* W; bf16* hi; int N, K, Kp, total; };
struct ConvBatch { ConvDesc d[10]; int nd; int grand; };

__global__ void conv_multi(ConvBatch cb)
{
    int i = blockIdx.x * blockDim.x + threadIdx.x;
    if (i >= cb.grand) return;
    int m = 0;
    while (i >= cb.d[m].total) { i -= cb.d[m].total; ++m; }
    const ConvDesc d = cb.d[m];
    int n = i / d.Kp, k = i % d.Kp;
    float v = (k < d.K) ? d.W[(size_t)k * d.N + n] : 0.f;
    bf16 h = __float2bfloat16(v);
    d.hi[i] = h;
    (d.hi + (size_t)d.N * d.Kp)[i] = __float2bfloat16(v - __bfloat162float(h));
}

// pad raw fp32 rows [rows][K] -> bf16 [rows][Kp] zero-padded
__global__ void pad_raw(const float* __restrict__ src, int K, int Kp, int rows,
                        bf16* __restrict__ out)
{
    int i = blockIdx.x * blockDim.x + threadIdx.x;
    if (i >= rows * Kp) return;
    int r = i / Kp, k = i % Kp;
    out[i] = __float2bfloat16(k < K ? src[(size_t)r * K + k] : 0.f);
}

// ---------------------------------------------------------------------------
// graph structure helpers
// ---------------------------------------------------------------------------
__global__ void zero_i32(int* __restrict__ p, int n) {
    int i = blockIdx.x * blockDim.x + threadIdx.x;
    if (i < n) p[i] = 0;
}
__global__ void copy_i32(const int* __restrict__ a, int* __restrict__ b, int n) {
    int i = blockIdx.x * blockDim.x + threadIdx.x;
    if (i < n) b[i] = a[i];
}
__global__ void count_edges(const int* __restrict__ src, const int* __restrict__ dst,
                            const int* __restrict__ node_batch,
                            int* __restrict__ cnt_s, int* __restrict__ cnt_d,
                            int* __restrict__ ebat)
{
    int i = blockIdx.x * blockDim.x + threadIdx.x;
    if (i >= N_EDGES) return;
    int s = src[i], d = dst[i];
    atomicAdd(&cnt_s[s], 1);
    atomicAdd(&cnt_d[d], 1);
    ebat[i] = node_batch[s];
}
__global__ void count_nodes(const int* __restrict__ node_batch, int* __restrict__ gcnt)
{
    int i = blockIdx.x * blockDim.x + threadIdx.x;
    if (i >= N_NODES) return;
    atomicAdd(&gcnt[node_batch[i]], 1);
}
__global__ __launch_bounds__(1024)
void scan_excl_kernel(const int* __restrict__ cnt, int* __restrict__ off, int n)
{
    __shared__ int part[1024];
    int t = threadIdx.x;
    int chunk = (n + 1023) >> 10;
    int lo = t * chunk; if (lo > n) lo = n;
    int hi = lo + chunk; if (hi > n) hi = n;
    int s = 0;
    for (int i = lo; i < hi; ++i) s += cnt[i];
    part[t] = s;
    __syncthreads();
    for (int d = 1; d < 1024; d <<= 1) {
        int v = (t >= d) ? part[t - d] : 0;
        __syncthreads();
        part[t] += v;
        __syncthreads();
    }
    int base = (t == 0) ? 0 : part[t - 1];
    for (int i = lo; i < hi; ++i) { off[i] = base; base += cnt[i]; }
    if (t == 1023) off[n] = part[1023];
}
__global__ void csr_fill(const int* __restrict__ src, const int* __restrict__ dst,
                         int* __restrict__ cur_s, int* __restrict__ cur_d,
                         int* __restrict__ idx_s, int* __restrict__ idx_d)
{
    int i = blockIdx.x * blockDim.x + threadIdx.x;
    if (i >= N_EDGES) return;
    int p = atomicAdd(&cur_s[src[i]], 1); idx_s[p] = i;
    int q = atomicAdd(&cur_d[dst[i]], 1); idx_d[q] = i;
}
// deterministic edge order: sort each node's edge list ascending (matches JAX
// segment_sum accumulation order; kills the atomic-order absmax roulette)
__global__ void sort_csr(const int* __restrict__ offs, int* __restrict__ idx, int n)
{
    int v = blockIdx.x * blockDim.x + threadIdx.x;
    if (v >= n) return;
    int k0 = offs[v], k1 = offs[v + 1];
    for (int i = k0 + 1; i < k1; ++i) {
        int x = idx[i], j = i - 1;
        while (j >= k0 && idx[j] > x) { idx[j + 1] = idx[j]; --j; }
        idx[j + 1] = x;
    }
}
// one wave per node, 4 nodes per block; ushort4 (8B) vector loads
__global__ void seg_sum_csr(const bf16* __restrict__ rows, const int* __restrict__ offs,
                            const int* __restrict__ idx, bf16* __restrict__ out)
{
    int n = blockIdx.x * 4 + (threadIdx.x >> 6);
    int lane = threadIdx.x & 63;
    if (n >= N_NODES) return;
    int k0 = offs[n], k1 = offs[n + 1];
    const unsigned short* rp = (const unsigned short*)rows;
    float s0 = 0.f, s1 = 0.f, s2 = 0.f, s3 = 0.f;
    for (int k = k0; k < k1; ++k) {
        us4 v = *(const us4*)(rp + (size_t)idx[k] * DD + lane * 4);
        s0 += bfbits2f(v.x); s1 += bfbits2f(v.y); s2 += bfbits2f(v.z); s3 += bfbits2f(v.w);
    }
    us4 o;
    o.x = f2bfbits(s0); o.y = f2bfbits(s1); o.z = f2bfbits(s2); o.w = f2bfbits(s3);
    *(us4*)((unsigned short*)out + (size_t)n * DD + lane * 4) = o;
}
// one wave per graph, 4 graphs per block
__global__ void range_sum(const bf16* __restrict__ rows, const int* __restrict__ gs,
                          bf16* __restrict__ out)
{
    int g = blockIdx.x * 4 + (threadIdx.x >> 6);
    int lane = threadIdx.x & 63;
    if (g >= N_GRAPH) return;
    int n0 = gs[g], n1 = gs[g + 1];
    const unsigned short* rp = (const unsigned short*)rows;
    float s0 = 0.f, s1 = 0.f, s2 = 0.f, s3 = 0.f;
    for (int n = n0; n < n1; ++n) {
        us4 v = *(const us4*)(rp + (size_t)n * DD + lane * 4);
        s0 += bfbits2f(v.x); s1 += bfbits2f(v.y); s2 += bfbits2f(v.z); s3 += bfbits2f(v.w);
    }
    us4 o;
    o.x = f2bfbits(s0); o.y = f2bfbits(s1); o.z = f2bfbits(s2); o.w = f2bfbits(s3);
    *(us4*)((unsigned short*)out + (size_t)g * DD + lane * 4) = o;
}
__global__ void u_init(bf16* __restrict__ u, const float* __restrict__ u0)
{
    int i = blockIdx.x * blockDim.x + threadIdx.x;
    if (i < N_GRAPH * DD) u[i] = __float2bfloat16(u0[i & (DD - 1)]);
}
__global__ void pos_head2(const bf16* __restrict__ ph, const float* __restrict__ W,
                          const float* __restrict__ b, float* __restrict__ pos,
                          int nrows, int write_mode)
{
    int gid = blockIdx.x * blockDim.x + threadIdx.x;
    int row = gid >> 6;
    int lane = threadIdx.x & 63;
    if (row >= nrows) return;
    const bf16* r = ph + (size_t)row * DD;
    float a0 = 0.f, a1 = 0.f, a2 = 0.f;
    for (int k = lane; k < DD; k += 64) {
        float v = __bfloat162float(r[k]);
        a0 += v * W[k * 3 + 0];
        a1 += v * W[k * 3 + 1];
        a2 += v * W[k * 3 + 2];
    }
#pragma unroll
    for (int d = 32; d > 0; d >>= 1) {
        a0 += __shfl_down(a0, d);
        a1 += __shfl_down(a1, d);
        a2 += __shfl_down(a2, d);
    }
    if (lane == 0) {
        float* p = pos + (size_t)row * 3;
        if (write_mode) {
            p[0] = a0 + b[0]; p[1] = a1 + b[1]; p[2] = a2 + b[2];
        } else {
            p[0] += a0 + b[0]; p[1] += a1 + b[1]; p[2] += a2 + b[2];
        }
    }
}

// ---------------------------------------------------------------------------
extern "C" void kernel_launch(void* const* d_in, const int* in_sizes, int n_in,
                              void* d_out, int out_size, void* d_ws, size_t ws_size,
                              hipStream_t stream)
{
    const float* x_raw    = (const float*)d_in[0];
    const float* edge_raw = (const float*)d_in[1];
    const float* u0       = (const float*)d_in[2];
    const float* enW1 = (const float*)d_in[3];  const float* enb1 = (const float*)d_in[4];
    const float* enW2 = (const float*)d_in[5];  const float* enb2 = (const float*)d_in[6];
    const float* enW3 = (const float*)d_in[7];  const float* enb3 = (const float*)d_in[8];
    const float* eeW1 = (const float*)d_in[9];  const float* eeb1 = (const float*)d_in[10];
    const float* eeW2 = (const float*)d_in[11]; const float* eeb2 = (const float*)d_in[12];
    const float* eeW3 = (const float*)d_in[13]; const float* eeb3 = (const float*)d_in[14];
    const float* eW1 = (const float*)d_in[15];  const float* eb1 = (const float*)d_in[16];
    const float* eW2 = (const float*)d_in[17];  const float* eb2 = (const float*)d_in[18];
    const float* eW3 = (const float*)d_in[19];  const float* eb3 = (const float*)d_in[20];
    const float* nW1 = (const float*)d_in[21];  const float* nb1 = (const float*)d_in[22];
    const float* nW2 = (const float*)d_in[23];  const float* nb2 = (const float*)d_in[24];
    const float* nW3 = (const float*)d_in[25];  const float* nb3 = (const float*)d_in[26];
    const float* gW1 = (const float*)d_in[27];  const float* gb1 = (const float*)d_in[28];
    const float* gW2 = (const float*)d_in[29];  const float* gb2 = (const float*)d_in[30];
    const float* gW3 = (const float*)d_in[31];  const float* gb3 = (const float*)d_in[32];
    const float* pW1 = (const float*)d_in[33];  const float* pb1 = (const float*)d_in[34];
    const float* pW2 = (const float*)d_in[35];  const float* pb2 = (const float*)d_in[36];
    const int* edge_index = (const int*)d_in[37];
    const int* node_batch = (const int*)d_in[38];
    const int* src = edge_index;
    const int* dst = edge_index + N_EDGES;
    float* pos = (float*)d_out;
    (void)in_sizes; (void)n_in; (void)out_size;

    // ---- workspace carve: fixed buffers first, then adaptive chunk buffers ----
    char* wp = (char*)d_ws;
    auto alloc = [&](size_t bytes) -> void* {
        void* r = (void*)wp;
        wp += (bytes + 255) & ~(size_t)255;
        return r;
    };
    bf16* x     = (bf16*)alloc((size_t)N_NODES * DD * 2);
    bf16* e     = (bf16*)alloc((size_t)N_EDGES * DD * 2);
    bf16* u     = (bf16*)alloc((size_t)N_GRAPH * DD * 2);
    bf16* sent  = (bf16*)alloc((size_t)N_NODES * DD * 2);
    bf16* recv  = (bf16*)alloc((size_t)N_NODES * DD * 2);
    bf16* gn    = (bf16*)alloc((size_t)N_GRAPH * DD * 2);
    bf16* ge    = (bf16*)alloc((size_t)N_GRAPH * DD * 2);
    bf16* gh1   = (bf16*)alloc((size_t)N_GRAPH * HH * 2);
    bf16* gh2   = (bf16*)alloc((size_t)N_GRAPH * HH * 2);
    bf16* wbuf  = (bf16*)alloc((size_t)6000000 * 2);        // hi/lo transposed weights (per-layer, reused)
    int* cnt_s  = (int*)alloc((size_t)N_NODES * 4);
    int* cnt_d  = (int*)alloc((size_t)N_NODES * 4);
    int* gcnt   = (int*)alloc((size_t)N_GRAPH * 4);
    int* off_s  = (int*)alloc((size_t)(N_NODES + 1) * 4);
    int* off_d  = (int*)alloc((size_t)(N_NODES + 1) * 4);
    int* gstart = (int*)alloc((size_t)(N_GRAPH + 1) * 4);
    int* cur_s  = (int*)alloc((size_t)N_NODES * 4);
    int* cur_d  = (int*)alloc((size_t)N_NODES * 4);
    int* idx_s  = (int*)alloc((size_t)N_EDGES * 4);
    int* idx_d  = (int*)alloc((size_t)N_EDGES * 4);
    int* ebat   = (int*)alloc((size_t)N_EDGES * 4);

    // adaptive chunk size: biggest of {50000, 25000, 12500} that fits ws.
    size_t used = (size_t)(wp - (char*)d_ws);
    size_t remain = ws_size > used ? ws_size - used : 0;
    auto pad256 = [](size_t b) { return (b + 255) & ~(size_t)255; };
    int EC = 12500;
    {
        const int ladder[3] = {50000, 25000, 12500};
        for (int i = 0; i < 3; ++i) {
            int c = ladder[i];
            size_t need = 2 * pad256((size_t)c * HH * 2) + pad256((size_t)c * 192 * 2);
            if (need <= remain) { EC = c; break; }
        }
    }
    const int NC = EC < N_NODES ? EC : N_NODES;   // node chunk (<=50000)
    bf16* h1   = (bf16*)alloc((size_t)EC * HH * 2);
    bf16* h2   = (bf16*)alloc((size_t)EC * HH * 2);
    bf16* rawp = (bf16*)alloc((size_t)EC * 192 * 2);   // padded raw-input chunk

    // ---- graph structure (rebuilt every call) ----
    zero_i32<<<(N_NODES + 255) / 256, 256, 0, stream>>>(cnt_s, N_NODES);
    zero_i32<<<(N_NODES + 255) / 256, 256, 0, stream>>>(cnt_d, N_NODES);
    zero_i32<<<(N_GRAPH + 255) / 256, 256, 0, stream>>>(gcnt, N_GRAPH);
    count_edges<<<(N_EDGES + 255) / 256, 256, 0, stream>>>(src, dst, node_batch, cnt_s, cnt_d, ebat);
    count_nodes<<<(N_NODES + 255) / 256, 256, 0, stream>>>(node_batch, gcnt);
    scan_excl_kernel<<<1, 1024, 0, stream>>>(cnt_s, off_s, N_NODES);
    scan_excl_kernel<<<1, 1024, 0, stream>>>(cnt_d, off_d, N_NODES);
    scan_excl_kernel<<<1, 1024, 0, stream>>>(gcnt, gstart, N_GRAPH);
    copy_i32<<<(N_NODES + 255) / 256, 256, 0, stream>>>(off_s, cur_s, N_NODES);
    copy_i32<<<(N_NODES + 255) / 256, 256, 0, stream>>>(off_d, cur_d, N_NODES);
    csr_fill<<<(N_EDGES + 255) / 256, 256, 0, stream>>>(src, dst, cur_s, cur_d, idx_s, idx_d);
    sort_csr<<<(N_NODES + 255) / 256, 256, 0, stream>>>(off_s, idx_s, N_NODES);
    sort_csr<<<(N_NODES + 255) / 256, 256, 0, stream>>>(off_d, idx_d, N_NODES);

    u_init<<<(N_GRAPH * DD + 255) / 256, 256, 0, stream>>>(u, u0);

    // batched weight conversion helper
    bf16* wb_cur = wbuf;
    ConvBatch cb; cb.nd = 0; cb.grand = 0;
    auto wreset = [&]() { wb_cur = wbuf; cb.nd = 0; cb.grand = 0; };
    auto wadd = [&](const float* W, int N, int K, int Kp) -> bf16* {
        bf16* hi = wb_cur;
        wb_cur += (size_t)N * Kp * 2;
        ConvDesc& d = cb.d[cb.nd++];
        d.W = W; d.hi = hi; d.N = N; d.K = K; d.Kp = Kp; d.total = N * Kp;
        cb.grand += d.total;
        return hi;
    };
    auto wflush = [&]() {
        conv_multi<<<(cb.grand + 255) / 256, 256, 0, stream>>>(cb);
    };
    auto wlo_of = [&](bf16* hi, int N, int Kp) -> bf16* { return hi + (size_t)N * Kp; };

    // ---- encoders ----
    wreset();
    bf16* cenW1 = wadd(enW1, HH, NODE_IN_F, 192);
    bf16* cenW2 = wadd(enW2, HH, HH, HH);
    bf16* cenW3 = wadd(enW3, DD, HH, HH);
    bf16* ceeW1 = wadd(eeW1, HH, EDGE_IN_F, 32);
    bf16* ceeW2 = wadd(eeW2, HH, HH, HH);
    bf16* ceeW3 = wadd(eeW3, DD, HH, HH);
    wflush();

    for (int off = 0; off < N_NODES; off += NC) {
        int cnt = (N_NODES - off) < NC ? (N_NODES - off) : NC;
        pad_raw<<<((size_t)cnt * 192 + 255) / 256, 256, 0, stream>>>(x_raw + (size_t)off * NODE_IN_F, NODE_IN_F, 192, cnt, rawp);
        { GMArgs g = gm_new(cnt, HH); gm_part(g, rawp, 192, nullptr, cenW1, wlo_of(cenW1, HH, 192), 192, 192);
          gm_run(stream, g, enb1, nullptr, h1, 1); }
        { GMArgs g = gm_new(cnt, HH); gm_part(g, h1, HH, nullptr, cenW2, wlo_of(cenW2, HH, HH), HH, HH);
          gm_run(stream, g, enb2, nullptr, h2, 1); }
        { GMArgs g = gm_new(cnt, DD); gm_part(g, h2, HH, nullptr, cenW3, wlo_of(cenW3, DD, HH), HH, HH);
          gm_run(stream, g, enb3, nullptr, x + (size_t)off * DD, 1); }
    }
    for (int off = 0; off < N_EDGES; off += EC) {
        int cnt = (N_EDGES - off) < EC ? (N_EDGES - off) : EC;
        pad_raw<<<((size_t)cnt * 32 + 255) / 256, 256, 0, stream>>>(edge_raw + (size_t)off * EDGE_IN_F, EDGE_IN_F, 32, cnt, rawp);
        { GMArgs g = gm_new(cnt, HH); gm_part(g, rawp, 32, nullptr, ceeW1, wlo_of(ceeW1, HH, 32), 32, 32);
          gm_run(stream, g, eeb1, nullptr, h1, 1); }
        { GMArgs g = gm_new(cnt, HH); gm_part(g, h1, HH, nullptr, ceeW2, wlo_of(ceeW2, HH, HH), HH, HH);
          gm_run(stream, g, eeb2, nullptr, h2, 1); }
        { GMArgs g = gm_new(cnt, DD); gm_part(g, h2, HH, nullptr, ceeW3, wlo_of(ceeW3, DD, HH), HH, HH);
          gm_run(stream, g, eeb3, nullptr, e + (size_t)off * DD, 1); }
    }

    // ---- L message-passing layers ----
    for (int l = 0; l < LL; ++l) {
        const float* ew1  = eW1 + (size_t)l * 4 * DD * HH;  const float* eb1l = eb1 + (size_t)l * HH;
        const float* ew2  = eW2 + (size_t)l * HH * HH;      const float* eb2l = eb2 + (size_t)l * HH;
        const float* ew3  = eW3 + (size_t)l * HH * DD;      const float* eb3l = eb3 + (size_t)l * DD;
        const float* nw1  = nW1 + (size_t)l * 4 * DD * HH;  const float* nb1l = nb1 + (size_t)l * HH;
        const float* nw2  = nW2 + (size_t)l * HH * HH;      const float* nb2l = nb2 + (size_t)l * HH;
        const float* nw3  = nW3 + (size_t)l * HH * DD;      const float* nb3l = nb3 + (size_t)l * DD;
        const float* gw1  = gW1 + (size_t)l * 3 * DD * HH;  const float* gb1l = gb1 + (size_t)l * HH;
        const float* gw2  = gW2 + (size_t)l * HH * HH;      const float* gb2l = gb2 + (size_t)l * HH;
        const float* gw3  = gW3 + (size_t)l * HH * DD;      const float* gb3l = gb3 + (size_t)l * DD;
        const float* pw1  = pW1 + (size_t)l * DD * DD;      const float* pb1l = pb1 + (size_t)l * DD;
        const float* pw2  = pW2 + (size_t)l * DD * 3;       const float* pb2l = pb2 + (size_t)l * 3;

        // convert this layer's weights (transposed, hi/lo) — one launch
        wreset();
        bf16* cew1 = wadd(ew1, HH, 4 * DD, 4 * DD);   // [512][1024]
        bf16* cew2 = wadd(ew2, HH, HH, HH);
        bf16* cew3 = wadd(ew3, DD, HH, HH);
        bf16* cnw1 = wadd(nw1, HH, 4 * DD, 4 * DD);
        bf16* cnw2 = wadd(nw2, HH, HH, HH);
        bf16* cnw3 = wadd(nw3, DD, HH, HH);
        bf16* cgw1 = wadd(gw1, HH, 3 * DD, 3 * DD);   // [512][768]
        bf16* cgw2 = wadd(gw2, HH, HH, HH);
        bf16* cgw3 = wadd(gw3, DD, HH, HH);
        bf16* cpw1 = wadd(pw1, DD, DD, DD);
        wflush();
        bf16* lew1 = wlo_of(cew1, HH, 4 * DD);
        bf16* lnw1 = wlo_of(cnw1, HH, 4 * DD);
        bf16* lgw1 = wlo_of(cgw1, HH, 3 * DD);

        // ---- edge update: e += MLP3(concat[e, x[src], x[dst], u[eb]]) ----
        for (int off = 0; off < N_EDGES; off += EC) {
            int cnt = (N_EDGES - off) < EC ? (N_EDGES - off) : EC;
            { GMArgs g = gm_new(cnt, HH);
              gm_part(g, e + (size_t)off * DD, DD, nullptr,    cew1,            lew1,            4 * DD, DD);
              gm_part(g, x,                    DD, src + off,  cew1 + 1 * DD,   lew1 + 1 * DD,   4 * DD, DD);
              gm_part(g, x,                    DD, dst + off,  cew1 + 2 * DD,   lew1 + 2 * DD,   4 * DD, DD);
              gm_part(g, u,                    DD, ebat + off, cew1 + 3 * DD,   lew1 + 3 * DD,   4 * DD, DD);
              gm_run(stream, g, eb1l, nullptr, h1, 1); }
            { GMArgs g = gm_new(cnt, HH); gm_part(g, h1, HH, nullptr, cew2, wlo_of(cew2, HH, HH), HH, HH);
              gm_run(stream, g, eb2l, nullptr, h2, 1); }
            { GMArgs g = gm_new(cnt, DD); gm_part(g, h2, HH, nullptr, cew3, wlo_of(cew3, DD, HH), HH, HH);
              gm_run(stream, g, eb3l, e + (size_t)off * DD, e + (size_t)off * DD, 1); }
        }

        // ---- node update ----
        seg_sum_csr<<<(N_NODES + 3) / 4, 256, 0, stream>>>(e, off_s, idx_s, sent);
        seg_sum_csr<<<(N_NODES + 3) / 4, 256, 0, stream>>>(e, off_d, idx_d, recv);
        for (int off = 0; off < N_NODES; off += NC) {
            int cnt = (N_NODES - off) < NC ? (N_NODES - off) : NC;
            { GMArgs g = gm_new(cnt, HH);
              gm_part(g, x    + (size_t)off * DD, DD, nullptr,          cnw1,          lnw1,          4 * DD, DD);
              gm_part(g, sent + (size_t)off * DD, DD, nullptr,          cnw1 + 1 * DD, lnw1 + 1 * DD, 4 * DD, DD);
              gm_part(g, recv + (size_t)off * DD, DD, nullptr,          cnw1 + 2 * DD, lnw1 + 2 * DD, 4 * DD, DD);
              gm_part(g, u,                       DD, node_batch + off, cnw1 + 3 * DD, lnw1 + 3 * DD, 4 * DD, DD);
              gm_run(stream, g, nb1l, nullptr, h1, 1); }
            { GMArgs g = gm_new(cnt, HH); gm_part(g, h1, HH, nullptr, cnw2, wlo_of(cnw2, HH, HH), HH, HH);
              gm_run(stream, g, nb2l, nullptr, h2, 1); }
            { GMArgs g = gm_new(cnt, DD); gm_part(g, h2, HH, nullptr, cnw3, wlo_of(cnw3, DD, HH), HH, HH);
              gm_run(stream, g, nb3l, x + (size_t)off * DD, x + (size_t)off * DD, 1); }
        }

        // ---- global update (ge == range-sum of `sent`) ----
        range_sum<<<(N_GRAPH + 3) / 4, 256, 0, stream>>>(x, gstart, gn);
        range_sum<<<(N_GRAPH + 3) / 4, 256, 0, stream>>>(sent, gstart, ge);
        { GMArgs g = gm_new(N_GRAPH, HH);
          gm_part(g, u,  DD, nullptr, cgw1,          lgw1,          3 * DD, DD);
          gm_part(g, gn, DD, nullptr, cgw1 + 1 * DD, lgw1 + 1 * DD, 3 * DD, DD);
          gm_part(g, ge, DD, nullptr, cgw1 + 2 * DD, lgw1 + 2 * DD, 3 * DD, DD);
          gm_run(stream, g, gb1l, nullptr, gh1, 1); }
        { GMArgs g = gm_new(N_GRAPH, HH); gm_part(g, gh1, HH, nullptr, cgw2, wlo_of(cgw2, HH, HH), HH, HH);
          gm_run(stream, g, gb2l, nullptr, gh2, 1); }
        { GMArgs g = gm_new(N_GRAPH, DD); gm_part(g, gh2, HH, nullptr, cgw3, wlo_of(cgw3, DD, HH), HH, HH);
          gm_run(stream, g, gb3l, u, u, 1); }

        // ---- position head (h1 reused as [cnt][DD]) ----
        for (int off = 0; off < N_NODES; off += NC) {
            int cnt = (N_NODES - off) < NC ? (N_NODES - off) : NC;
            { GMArgs g = gm_new(cnt, DD); gm_part(g, x + (size_t)off * DD, DD, nullptr, cpw1, wlo_of(cpw1, DD, DD), DD, DD);
              gm_run(stream, g, pb1l, nullptr, h1, 1); }
            pos_head2<<<((size_t)cnt * 64 + 255) / 256, 256, 0, stream>>>(
                h1, pw2, pb2l, pos + (size_t)off * 3, cnt, l == 0 ? 1 : 0);
        }
    }
}

// Round 6
// 22611.607 us; speedup vs baseline: 1.0386x; 1.0386x over previous
//
#include <hip/hip_runtime.h>
#include <hip/hip_bf16.h>
#include <cstdint>
#include <cstddef>

#define N_NODES 50000
#define N_EDGES 200000
#define N_GRAPH 2048
#define DD 256
#define HH 512
#define LL 12
#define NODE_IN_F 173
#define EDGE_IN_F 13

typedef __hip_bfloat16 bf16;
typedef __attribute__((ext_vector_type(8))) short short8;
typedef __attribute__((ext_vector_type(4))) float f32x4;
typedef __attribute__((ext_vector_type(4))) unsigned short us4;

__device__ __forceinline__ float bfbits2f(unsigned short u) {
    return __uint_as_float(((unsigned)u) << 16);
}
__device__ __forceinline__ unsigned short f2bfbits(float f) {
    bf16 h = __float2bfloat16(f);
    return __builtin_bit_cast(unsigned short, h);
}

// async global->LDS 16B per lane; LDS dest = wave-uniform base + lane*16
__device__ __forceinline__ void gld16(const void* g, void* l) {
    __builtin_amdgcn_global_load_lds(
        (const __attribute__((address_space(1))) unsigned int*)g,
        (__attribute__((address_space(3))) unsigned int*)l, 16, 0, 0);
}

// ---------------------------------------------------------------------------
// MFMA multi-part gather GEMM with hi/lo-split bf16 weights.
//   C[M,N] = act( sum_p A_p[idx_p? idx_p[r]:r, :Kp] @ (Whi_p + Wlo_p)^T + bias ) (+res)
//
// 256x128 tile, 512 threads (8 waves: 4 row-waves x 2 col-waves, 64x64 each).
// QUAD-buffered LDS (128 KB), depth-3 prefetch, counted s_waitcnt vmcnt(8/4/0)
// + raw s_barrier. Gather indices preloaded to registers (no vmem in stage).
//
// LDS 16B-granule swizzle (rule #21 both-sides): unswizzled, a wave's
// ds_read_b128 puts 64 lanes (16 rows x 4 granules) on 8 bank-quad slots
// (bank = 16r+4g mod 32) = 8-way conflict (~2.9x). Swizzle: LDS slot s of
// row r holds global K-granule (s-(r>>1))&3; stage sources granule
// gq=(qq-(rq>>1))&3, reads use slot sq=(quad+((row>>1)&3))&3. Each register
// receives bit-identical data; 2 lanes/slot = conflict-free (m136).
// Epilogue: per-wave LDS transpose (stride 68 f32) -> 2x16B coalesced stores.
// ---------------------------------------------------------------------------
#define TBM 256
#define TBN 128

struct GMArgs {
    const bf16* A[4];
    const int*  idx[4];
    const bf16* whi[4];
    const bf16* wlo[4];
    int lda[4];
    int ldw[4];
    int Kp[4];
    int nparts;
    int M, N;            // ldc == N
    const float* bias;
    const bf16* res;     // row stride N
    bf16* C;
    int relu;
};

__global__ __launch_bounds__(512)
void gemm_mfma(GMArgs g)
{
    __shared__ __align__(16) short AsL[4 * TBM * 32];   // 64 KB
    __shared__ __align__(16) short BhL[4 * TBN * 32];   // 32 KB
    __shared__ __align__(16) short BlL[4 * TBN * 32];   // 32 KB

    const int tid  = threadIdx.x;
    const int lane = tid & 63;
    const int wv   = tid >> 6;          // 0..7
    const int wm   = (wv >> 1) * 64;    // wave row offset: 0/64/128/192
    const int wn   = (wv & 1) * 64;     // wave col offset: 0/64
    const int quad = lane >> 4;
    const int l16  = lane & 15;
    const int rq   = lane >> 2;         // staging: row-within-slab 0..15
    const int qq   = lane & 3;          // staging: 16B quarter 0..3
    // LDS granule swizzle (verified bijection; see header comment)
    const int gq   = (qq - (rq >> 1)) & 3;            // stage: global granule for slot qq
    const int sq   = (quad + ((l16 >> 1) & 3)) & 3;   // read: slot holding granule `quad`

    // XCD-aware bijective swizzle (m204)
    const int gx  = gridDim.x;
    const int nwg = gx * gridDim.y;
    int hw  = blockIdx.y * gx + blockIdx.x;
    int xcd = hw & 7, rk = hw >> 3;
    int q = nwg >> 3, r = nwg & 7;
    int lid = (xcd < r ? xcd * (q + 1) : r * (q + 1) + (xcd - r) * q) + rk;
    const int row0 = (lid / gx) * TBM;
    const int col0 = (lid % gx) * TBN;

    // flatten (part, k-step) into step index t = 0..T-1
    int steps[4]; int T = 0;
#pragma unroll
    for (int p = 0; p < 4; ++p) { steps[p] = (p < g.nparts) ? (g.Kp[p] >> 5) : 0; T += steps[p]; }

    // preload K-independent gather row indices (waves 0..3 own the A slabs)
    int pa0[4], pa1[4], pa2[4], pa3[4];
#pragma unroll
    for (int s = 0; s < 4; ++s) {
        int sid = wv * 4 + s;
        int r2 = (sid & 15) * 16 + rq;
        int grr = row0 + r2;
        int cr = grr < g.M ? grr : g.M - 1;   // clamp: deterministic load count
        pa0[s] = (g.nparts > 0 && g.idx[0]) ? g.idx[0][cr] : cr;
        pa1[s] = (g.nparts > 1 && g.idx[1]) ? g.idx[1][cr] : cr;
        pa2[s] = (g.nparts > 2 && g.idx[2]) ? g.idx[2][cr] : cr;
        pa3[s] = (g.nparts > 3 && g.idx[3]) ? g.idx[3][cr] : cr;
    }

    f32x4 acc[4][4];
#pragma unroll
    for (int i = 0; i < 4; ++i)
#pragma unroll
        for (int j = 0; j < 4; ++j)
            acc[i][j] = (f32x4){0.f, 0.f, 0.f, 0.f};

    // 32 slabs/stage: sid 0..15 = A rows sid*16; 16..23 = Bh; 24..31 = Bl.
    // wave wv handles sid = wv*4 + s  (wave-uniform branches, 4 gld16/wave)
    auto stage = [&](int t, int b) {
        int p = 0, tt = t;
        while (tt >= steps[p]) { tt -= steps[p]; ++p; }
        const int k0 = tt << 5;
        const short* Ap  = (const short*)g.A[p];
        const short* Whi = (const short*)g.whi[p];
        const short* Wlo = (const short*)g.wlo[p];
        const int lda = g.lda[p];
        const int ldw = g.ldw[p];
        const int kcol = k0 + gq * 8;     // swizzled source granule
#pragma unroll
        for (int s = 0; s < 4; ++s) {
            const int sid = wv * 4 + s;
            if (sid < 16) {
                int ar = (p == 0) ? pa0[s] : (p == 1) ? pa1[s] : (p == 2) ? pa2[s] : pa3[s];
                gld16(Ap + (size_t)ar * lda + kcol,
                      AsL + (size_t)b * (TBM * 32) + sid * (16 * 32));
            } else if (sid < 24) {
                int r2 = (sid - 16) * 16 + rq;
                gld16(Whi + (size_t)(col0 + r2) * ldw + kcol,
                      BhL + (size_t)b * (TBN * 32) + (sid - 16) * (16 * 32));
            } else {
                int r2 = (sid - 24) * 16 + rq;
                gld16(Wlo + (size_t)(col0 + r2) * ldw + kcol,
                      BlL + (size_t)b * (TBN * 32) + (sid - 24) * (16 * 32));
            }
        }
    };

    stage(0, 0);
    if (T > 1) stage(1, 1);
    if (T > 2) stage(2, 2);
    for (int t = 0; t < T; ++t) {
        // certify stage-t landed; keep up to 2 newer stages (8 loads) in flight
        if (t + 2 < T)      asm volatile("s_waitcnt vmcnt(8)" ::: "memory");
        else if (t + 1 < T) asm volatile("s_waitcnt vmcnt(4)" ::: "memory");
        else                asm volatile("s_waitcnt vmcnt(0)" ::: "memory");
        __builtin_amdgcn_s_barrier();   // stage-t visible to all; buf (t+3)&3 free
        asm volatile("" ::: "memory");
        if (t + 3 < T) stage(t + 3, (t + 3) & 3);

        const int cur = t & 3;
        const short* Ab = AsL + (size_t)cur * (TBM * 32);
        const short* Bhb = BhL + (size_t)cur * (TBN * 32);
        const short* Blb = BlL + (size_t)cur * (TBN * 32);
        short8 a[4], bh[4], bl[4];
#pragma unroll
        for (int i = 0; i < 4; ++i)
            a[i] = *(const short8*)&Ab[(wm + i * 16 + l16) * 32 + sq * 8];
#pragma unroll
        for (int j = 0; j < 4; ++j) {
            bh[j] = *(const short8*)&Bhb[(wn + j * 16 + l16) * 32 + sq * 8];
            bl[j] = *(const short8*)&Blb[(wn + j * 16 + l16) * 32 + sq * 8];
        }
#pragma unroll
        for (int i = 0; i < 4; ++i)
#pragma unroll
            for (int j = 0; j < 4; ++j)
                acc[i][j] = __builtin_amdgcn_mfma_f32_16x16x32_bf16(a[i], bh[j], acc[i][j], 0, 0, 0);
#pragma unroll
        for (int i = 0; i < 4; ++i)
#pragma unroll
            for (int j = 0; j < 4; ++j)
                acc[i][j] = __builtin_amdgcn_mfma_f32_16x16x32_bf16(a[i], bl[j], acc[i][j], 0, 0, 0);
    }

    // ---- epilogue: per-wave LDS transpose -> coalesced 16B stores ----
    __syncthreads();   // all LDS reads done; reuse AsL as scratch
    {
        const int SROW = 68;                                  // padded f32 stride
        float* Sw = (float*)AsL + wv * (16 * SROW);           // per-wave [16][68]
        const int erow = lane >> 2;                           // 0..15
        const int ecb  = lane & 3;                            // 16-col block
        float bc[4];
#pragma unroll
        for (int j = 0; j < 4; ++j)
            bc[j] = g.bias ? g.bias[col0 + wn + j * 16 + l16] : 0.f;
        const int grb = row0 + wm;
#pragma unroll
        for (int i = 0; i < 4; ++i) {
#pragma unroll
            for (int j = 0; j < 4; ++j)
#pragma unroll
                for (int r3 = 0; r3 < 4; ++r3) {
                    float v = acc[i][j][r3] + bc[j];
                    if (g.relu) v = fmaxf(v, 0.f);
                    Sw[(quad * 4 + r3) * SROW + j * 16 + l16] = v;
                }
            int gr = grb + i * 16 + erow;
            if (gr < g.M) {
                const float* sr = Sw + erow * SROW + ecb * 16;
                f32x4 q0 = *(const f32x4*)(sr + 0);
                f32x4 q1 = *(const f32x4*)(sr + 4);
                f32x4 q2 = *(const f32x4*)(sr + 8);
                f32x4 q3 = *(const f32x4*)(sr + 12);
                size_t ob = (size_t)gr * g.N + col0 + wn + ecb * 16;
                float v[16];
                *(f32x4*)&v[0] = q0; *(f32x4*)&v[4] = q1;
                *(f32x4*)&v[8] = q2; *(f32x4*)&v[12] = q3;
                if (g.res) {
                    const short* rp = (const short*)g.res + ob;
                    short8 r0 = *(const short8*)rp;
                    short8 r1 = *(const short8*)(rp + 8);
#pragma unroll
                    for (int k = 0; k < 8; ++k) {
                        v[k]     += bfbits2f((unsigned short)r0[k]);
                        v[8 + k] += bfbits2f((unsigned short)r1[k]);
                    }
                }
                short8 o0, o1;
#pragma unroll
                for (int k = 0; k < 8; ++k) {
                    o0[k] = (short)f2bfbits(v[k]);
                    o1[k] = (short)f2bfbits(v[8 + k]);
                }
                short* cp = (short*)g.C + ob;
                *(short8*)cp = o0;
                *(short8*)(cp + 8) = o1;
            }
        }
    }
}

// host-side builders
static inline GMArgs gm_new(int M, int N) {
    GMArgs g;
    for (int i = 0; i < 4; ++i) { g.A[i] = nullptr; g.idx[i] = nullptr; g.whi[i] = nullptr; g.wlo[i] = nullptr; g.lda[i] = 0; g.ldw[i] = 0; g.Kp[i] = 0; }
    g.nparts = 0; g.M = M; g.N = N; g.bias = nullptr; g.res = nullptr; g.C = nullptr; g.relu = 0;
    return g;
}
static inline void gm_part(GMArgs& g, const bf16* A, int lda, const int* idx,
                           const bf16* whi, const bf16* wlo, int ldw, int Kp) {
    int p = g.nparts++;
    g.A[p] = A; g.lda[p] = lda; g.idx[p] = idx; g.whi[p] = whi; g.wlo[p] = wlo; g.ldw[p] = ldw; g.Kp[p] = Kp;
}
static inline void gm_run(hipStream_t s, GMArgs& g, const float* bias,
                          const bf16* res, bf16* C, int relu) {
    g.bias = bias; g.res = res; g.C = C; g.relu = relu;
    dim3 grid(g.N / TBN, (g.M + TBM - 1) / TBM);
    gemm_mfma<<<grid, dim3(512), 0, s>>>(g);
}

// ---------------------------------------------------------------------------
// batched weight convert: W fp32 [K][N] -> Whi/Wlo bf16 [N][Kp] (transposed, padded)
// ---------------------------------------------------------------------------
struct ConvDesc { const float* W; bf16* hi; int N, K, Kp, total; };
struct ConvBatch { ConvDesc d[10]; int nd; int grand; };

__global__ void conv_multi(ConvBatch cb)
{
    int i = blockIdx.x * blockDim.x + threadIdx.x;
    if (i >= cb.grand) return;
    int m = 0;
    while (i >= cb.d[m].total) { i -= cb.d[m].total; ++m; }
    const ConvDesc d = cb.d[m];
    int n = i / d.Kp, k = i % d.Kp;
    float v = (k < d.K) ? d.W[(size_t)k * d.N + n] : 0.f;
    bf16 h = __float2bfloat16(v);
    d.hi[i] = h;
    (d.hi + (size_t)d.N * d.Kp)[i] = __float2bfloat16(v - __bfloat162float(h));
}

// pad raw fp32 rows [rows][K] -> bf16 [rows][Kp] zero-padded
__global__ void pad_raw(const float* __restrict__ src, int K, int Kp, int rows,
                        bf16* __restrict__ out)
{
    int i = blockIdx.x * blockDim.x + threadIdx.x;
    if (i >= rows * Kp) return;
    int r = i / Kp, k = i % Kp;
    out[i] = __float2bfloat16(k < K ? src[(size_t)r * K + k] : 0.f);
}

// ---------------------------------------------------------------------------
// graph structure helpers
// ---------------------------------------------------------------------------
__global__ void zero_i32(int* __restrict__ p, int n) {
    int i = blockIdx.x * blockDim.x + threadIdx.x;
    if (i < n) p[i] = 0;
}
__global__ void copy_i32(const int* __restrict__ a, int* __restrict__ b, int n) {
    int i = blockIdx.x * blockDim.x + threadIdx.x;
    if (i < n) b[i] = a[i];
}
__global__ void count_edges(const int* __restrict__ src, const int* __restrict__ dst,
                            const int* __restrict__ node_batch,
                            int* __restrict__ cnt_s, int* __restrict__ cnt_d,
                            int* __restrict__ ebat)
{
    int i = blockIdx.x * blockDim.x + threadIdx.x;
    if (i >= N_EDGES) return;
    int s = src[i], d = dst[i];
    atomicAdd(&cnt_s[s], 1);
    atomicAdd(&cnt_d[d], 1);
    ebat[i] = node_batch[s];
}
__global__ void count_nodes(const int* __restrict__ node_batch, int* __restrict__ gcnt)
{
    int i = blockIdx.x * blockDim.x + threadIdx.x;
    if (i >= N_NODES) return;
    atomicAdd(&gcnt[node_batch[i]], 1);
}
__global__ __launch_bounds__(1024)
void scan_excl_kernel(const int* __restrict__ cnt, int* __restrict__ off, int n)
{
    __shared__ int part[1024];
    int t = threadIdx.x;
    int chunk = (n + 1023) >> 10;
    int lo = t * chunk; if (lo > n) lo = n;
    int hi = lo + chunk; if (hi > n) hi = n;
    int s = 0;
    for (int i = lo; i < hi; ++i) s += cnt[i];
    part[t] = s;
    __syncthreads();
    for (int d = 1; d < 1024; d <<= 1) {
        int v = (t >= d) ? part[t - d] : 0;
        __syncthreads();
        part[t] += v;
        __syncthreads();
    }
    int base = (t == 0) ? 0 : part[t - 1];
    for (int i = lo; i < hi; ++i) { off[i] = base; base += cnt[i]; }
    if (t == 1023) off[n] = part[1023];
}
__global__ void csr_fill(const int* __restrict__ src, const int* __restrict__ dst,
                         int* __restrict__ cur_s, int* __restrict__ cur_d,
                         int* __restrict__ idx_s, int* __restrict__ idx_d)
{
    int i = blockIdx.x * blockDim.x + threadIdx.x;
    if (i >= N_EDGES) return;
    int p = atomicAdd(&cur_s[src[i]], 1); idx_s[p] = i;
    int q = atomicAdd(&cur_d[dst[i]], 1); idx_d[q] = i;
}
// deterministic edge order: sort each node's edge list ascending (matches JAX
// segment_sum accumulation order; kills the atomic-order absmax roulette)
__global__ void sort_csr(const int* __restrict__ offs, int* __restrict__ idx, int n)
{
    int v = blockIdx.x * blockDim.x + threadIdx.x;
    if (v >= n) return;
    int k0 = offs[v], k1 = offs[v + 1];
    for (int i = k0 + 1; i < k1; ++i) {
        int x = idx[i], j = i - 1;
        while (j >= k0 && idx[j] > x) { idx[j + 1] = idx[j]; --j; }
        idx[j + 1] = x;
    }
}
// one wave per node, 4 nodes per block; ushort4 (8B) vector loads
__global__ void seg_sum_csr(const bf16* __restrict__ rows, const int* __restrict__ offs,
                            const int* __restrict__ idx, bf16* __restrict__ out)
{
    int n = blockIdx.x * 4 + (threadIdx.x >> 6);
    int lane = threadIdx.x & 63;
    if (n >= N_NODES) return;
    int k0 = offs[n], k1 = offs[n + 1];
    const unsigned short* rp = (const unsigned short*)rows;
    float s0 = 0.f, s1 = 0.f, s2 = 0.f, s3 = 0.f;
    for (int k = k0; k < k1; ++k) {
        us4 v = *(const us4*)(rp + (size_t)idx[k] * DD + lane * 4);
        s0 += bfbits2f(v.x); s1 += bfbits2f(v.y); s2 += bfbits2f(v.z); s3 += bfbits2f(v.w);
    }
    us4 o;
    o.x = f2bfbits(s0); o.y = f2bfbits(s1); o.z = f2bfbits(s2); o.w = f2bfbits(s3);
    *(us4*)((unsigned short*)out + (size_t)n * DD + lane * 4) = o;
}
// one wave per graph, 4 graphs per block
__global__ void range_sum(const bf16* __restrict__ rows, const int* __restrict__ gs,
                          bf16* __restrict__ out)
{
    int g = blockIdx.x * 4 + (threadIdx.x >> 6);
    int lane = threadIdx.x & 63;
    if (g >= N_GRAPH) return;
    int n0 = gs[g], n1 = gs[g + 1];
    const unsigned short* rp = (const unsigned short*)rows;
    float s0 = 0.f, s1 = 0.f, s2 = 0.f, s3 = 0.f;
    for (int n = n0; n < n1; ++n) {
        us4 v = *(const us4*)(rp + (size_t)n * DD + lane * 4);
        s0 += bfbits2f(v.x); s1 += bfbits2f(v.y); s2 += bfbits2f(v.z); s3 += bfbits2f(v.w);
    }
    us4 o;
    o.x = f2bfbits(s0); o.y = f2bfbits(s1); o.z = f2bfbits(s2); o.w = f2bfbits(s3);
    *(us4*)((unsigned short*)out + (size_t)g * DD + lane * 4) = o;
}
__global__ void u_init(bf16* __restrict__ u, const float* __restrict__ u0)
{
    int i = blockIdx.x * blockDim.x + threadIdx.x;
    if (i < N_GRAPH * DD) u[i] = __float2bfloat16(u0[i & (DD - 1)]);
}
__global__ void pos_head2(const bf16* __restrict__ ph, const float* __restrict__ W,
                          const float* __restrict__ b, float* __restrict__ pos,
                          int nrows, int write_mode)
{
    int gid = blockIdx.x * blockDim.x + threadIdx.x;
    int row = gid >> 6;
    int lane = threadIdx.x & 63;
    if (row >= nrows) return;
    const bf16* r = ph + (size_t)row * DD;
    float a0 = 0.f, a1 = 0.f, a2 = 0.f;
    for (int k = lane; k < DD; k += 64) {
        float v = __bfloat162float(r[k]);
        a0 += v * W[k * 3 + 0];
        a1 += v * W[k * 3 + 1];
        a2 += v * W[k * 3 + 2];
    }
#pragma unroll
    for (int d = 32; d > 0; d >>= 1) {
        a0 += __shfl_down(a0, d);
        a1 += __shfl_down(a1, d);
        a2 += __shfl_down(a2, d);
    }
    if (lane == 0) {
        float* p = pos + (size_t)row * 3;
        if (write_mode) {
            p[0] = a0 + b[0]; p[1] = a1 + b[1]; p[2] = a2 + b[2];
        } else {
            p[0] += a0 + b[0]; p[1] += a1 + b[1]; p[2] += a2 + b[2];
        }
    }
}

// ---------------------------------------------------------------------------
extern "C" void kernel_launch(void* const* d_in, const int* in_sizes, int n_in,
                              void* d_out, int out_size, void* d_ws, size_t ws_size,
                              hipStream_t stream)
{
    const float* x_raw    = (const float*)d_in[0];
    const float* edge_raw = (const float*)d_in[1];
    const float* u0       = (const float*)d_in[2];
    const float* enW1 = (const float*)d_in[3];  const float* enb1 = (const float*)d_in[4];
    const float* enW2 = (const float*)d_in[5];  const float* enb2 = (const float*)d_in[6];
    const float* enW3 = (const float*)d_in[7];  const float* enb3 = (const float*)d_in[8];
    const float* eeW1 = (const float*)d_in[9];  const float* eeb1 = (const float*)d_in[10];
    const float* eeW2 = (const float*)d_in[11]; const float* eeb2 = (const float*)d_in[12];
    const float* eeW3 = (const float*)d_in[13]; const float* eeb3 = (const float*)d_in[14];
    const float* eW1 = (const float*)d_in[15];  const float* eb1 = (const float*)d_in[16];
    const float* eW2 = (const float*)d_in[17];  const float* eb2 = (const float*)d_in[18];
    const float* eW3 = (const float*)d_in[19];  const float* eb3 = (const float*)d_in[20];
    const float* nW1 = (const float*)d_in[21];  const float* nb1 = (const float*)d_in[22];
    const float* nW2 = (const float*)d_in[23];  const float* nb2 = (const float*)d_in[24];
    const float* nW3 = (const float*)d_in[25];  const float* nb3 = (const float*)d_in[26];
    const float* gW1 = (const float*)d_in[27];  const float* gb1 = (const float*)d_in[28];
    const float* gW2 = (const float*)d_in[29];  const float* gb2 = (const float*)d_in[30];
    const float* gW3 = (const float*)d_in[31];  const float* gb3 = (const float*)d_in[32];
    const float* pW1 = (const float*)d_in[33];  const float* pb1 = (const float*)d_in[34];
    const float* pW2 = (const float*)d_in[35];  const float* pb2 = (const float*)d_in[36];
    const int* edge_index = (const int*)d_in[37];
    const int* node_batch = (const int*)d_in[38];
    const int* src = edge_index;
    const int* dst = edge_index + N_EDGES;
    float* pos = (float*)d_out;
    (void)in_sizes; (void)n_in; (void)out_size;

    // ---- workspace carve: fixed buffers first, then adaptive chunk buffers ----
    char* wp = (char*)d_ws;
    auto alloc = [&](size_t bytes) -> void* {
        void* r = (void*)wp;
        wp += (bytes + 255) & ~(size_t)255;
        return r;
    };
    bf16* x     = (bf16*)alloc((size_t)N_NODES * DD * 2);
    bf16* e     = (bf16*)alloc((size_t)N_EDGES * DD * 2);
    bf16* u     = (bf16*)alloc((size_t)N_GRAPH * DD * 2);
    bf16* sent  = (bf16*)alloc((size_t)N_NODES * DD * 2);
    bf16* recv  = (bf16*)alloc((size_t)N_NODES * DD * 2);
    bf16* gn    = (bf16*)alloc((size_t)N_GRAPH * DD * 2);
    bf16* ge    = (bf16*)alloc((size_t)N_GRAPH * DD * 2);
    bf16* gh1   = (bf16*)alloc((size_t)N_GRAPH * HH * 2);
    bf16* gh2   = (bf16*)alloc((size_t)N_GRAPH * HH * 2);
    bf16* wbuf  = (bf16*)alloc((size_t)6000000 * 2);        // hi/lo transposed weights (per-layer, reused)
    int* cnt_s  = (int*)alloc((size_t)N_NODES * 4);
    int* cnt_d  = (int*)alloc((size_t)N_NODES * 4);
    int* gcnt   = (int*)alloc((size_t)N_GRAPH * 4);
    int* off_s  = (int*)alloc((size_t)(N_NODES + 1) * 4);
    int* off_d  = (int*)alloc((size_t)(N_NODES + 1) * 4);
    int* gstart = (int*)alloc((size_t)(N_GRAPH + 1) * 4);
    int* cur_s  = (int*)alloc((size_t)N_NODES * 4);
    int* cur_d  = (int*)alloc((size_t)N_NODES * 4);
    int* idx_s  = (int*)alloc((size_t)N_EDGES * 4);
    int* idx_d  = (int*)alloc((size_t)N_EDGES * 4);
    int* ebat   = (int*)alloc((size_t)N_EDGES * 4);

    // adaptive chunk size: biggest of {50000, 25000, 12500} that fits ws.
    size_t used = (size_t)(wp - (char*)d_ws);
    size_t remain = ws_size > used ? ws_size - used : 0;
    auto pad256 = [](size_t b) { return (b + 255) & ~(size_t)255; };
    int EC = 12500;
    {
        const int ladder[3] = {50000, 25000, 12500};
        for (int i = 0; i < 3; ++i) {
            int c = ladder[i];
            size_t need = 2 * pad256((size_t)c * HH * 2) + pad256((size_t)c * 192 * 2);
            if (need <= remain) { EC = c; break; }
        }
    }
    const int NC = EC < N_NODES ? EC : N_NODES;   // node chunk (<=50000)
    bf16* h1   = (bf16*)alloc((size_t)EC * HH * 2);
    bf16* h2   = (bf16*)alloc((size_t)EC * HH * 2);
    bf16* rawp = (bf16*)alloc((size_t)EC * 192 * 2);   // padded raw-input chunk

    // ---- graph structure (rebuilt every call) ----
    zero_i32<<<(N_NODES + 255) / 256, 256, 0, stream>>>(cnt_s, N_NODES);
    zero_i32<<<(N_NODES + 255) / 256, 256, 0, stream>>>(cnt_d, N_NODES);
    zero_i32<<<(N_GRAPH + 255) / 256, 256, 0, stream>>>(gcnt, N_GRAPH);
    count_edges<<<(N_EDGES + 255) / 256, 256, 0, stream>>>(src, dst, node_batch, cnt_s, cnt_d, ebat);
    count_nodes<<<(N_NODES + 255) / 256, 256, 0, stream>>>(node_batch, gcnt);
    scan_excl_kernel<<<1, 1024, 0, stream>>>(cnt_s, off_s, N_NODES);
    scan_excl_kernel<<<1, 1024, 0, stream>>>(cnt_d, off_d, N_NODES);
    scan_excl_kernel<<<1, 1024, 0, stream>>>(gcnt, gstart, N_GRAPH);
    copy_i32<<<(N_NODES + 255) / 256, 256, 0, stream>>>(off_s, cur_s, N_NODES);
    copy_i32<<<(N_NODES + 255) / 256, 256, 0, stream>>>(off_d, cur_d, N_NODES);
    csr_fill<<<(N_EDGES + 255) / 256, 256, 0, stream>>>(src, dst, cur_s, cur_d, idx_s, idx_d);
    sort_csr<<<(N_NODES + 255) / 256, 256, 0, stream>>>(off_s, idx_s, N_NODES);
    sort_csr<<<(N_NODES + 255) / 256, 256, 0, stream>>>(off_d, idx_d, N_NODES);

    u_init<<<(N_GRAPH * DD + 255) / 256, 256, 0, stream>>>(u, u0);

    // batched weight conversion helper
    bf16* wb_cur = wbuf;
    ConvBatch cb; cb.nd = 0; cb.grand = 0;
    auto wreset = [&]() { wb_cur = wbuf; cb.nd = 0; cb.grand = 0; };
    auto wadd = [&](const float* W, int N, int K, int Kp) -> bf16* {
        bf16* hi = wb_cur;
        wb_cur += (size_t)N * Kp * 2;
        ConvDesc& d = cb.d[cb.nd++];
        d.W = W; d.hi = hi; d.N = N; d.K = K; d.Kp = Kp; d.total = N * Kp;
        cb.grand += d.total;
        return hi;
    };
    auto wflush = [&]() {
        conv_multi<<<(cb.grand + 255) / 256, 256, 0, stream>>>(cb);
    };
    auto wlo_of = [&](bf16* hi, int N, int Kp) -> bf16* { return hi + (size_t)N * Kp; };

    // ---- encoders ----
    wreset();
    bf16* cenW1 = wadd(enW1, HH, NODE_IN_F, 192);
    bf16* cenW2 = wadd(enW2, HH, HH, HH);
    bf16* cenW3 = wadd(enW3, DD, HH, HH);
    bf16* ceeW1 = wadd(eeW1, HH, EDGE_IN_F, 32);
    bf16* ceeW2 = wadd(eeW2, HH, HH, HH);
    bf16* ceeW3 = wadd(eeW3, DD, HH, HH);
    wflush();

    for (int off = 0; off < N_NODES; off += NC) {
        int cnt = (N_NODES - off) < NC ? (N_NODES - off) : NC;
        pad_raw<<<((size_t)cnt * 192 + 255) / 256, 256, 0, stream>>>(x_raw + (size_t)off * NODE_IN_F, NODE_IN_F, 192, cnt, rawp);
        { GMArgs g = gm_new(cnt, HH); gm_part(g, rawp, 192, nullptr, cenW1, wlo_of(cenW1, HH, 192), 192, 192);
          gm_run(stream, g, enb1, nullptr, h1, 1); }
        { GMArgs g = gm_new(cnt, HH); gm_part(g, h1, HH, nullptr, cenW2, wlo_of(cenW2, HH, HH), HH, HH);
          gm_run(stream, g, enb2, nullptr, h2, 1); }
        { GMArgs g = gm_new(cnt, DD); gm_part(g, h2, HH, nullptr, cenW3, wlo_of(cenW3, DD, HH), HH, HH);
          gm_run(stream, g, enb3, nullptr, x + (size_t)off * DD, 1); }
    }
    for (int off = 0; off < N_EDGES; off += EC) {
        int cnt = (N_EDGES - off) < EC ? (N_EDGES - off) : EC;
        pad_raw<<<((size_t)cnt * 32 + 255) / 256, 256, 0, stream>>>(edge_raw + (size_t)off * EDGE_IN_F, EDGE_IN_F, 32, cnt, rawp);
        { GMArgs g = gm_new(cnt, HH); gm_part(g, rawp, 32, nullptr, ceeW1, wlo_of(ceeW1, HH, 32), 32, 32);
          gm_run(stream, g, eeb1, nullptr, h1, 1); }
        { GMArgs g = gm_new(cnt, HH); gm_part(g, h1, HH, nullptr, ceeW2, wlo_of(ceeW2, HH, HH), HH, HH);
          gm_run(stream, g, eeb2, nullptr, h2, 1); }
        { GMArgs g = gm_new(cnt, DD); gm_part(g, h2, HH, nullptr, ceeW3, wlo_of(ceeW3, DD, HH), HH, HH);
          gm_run(stream, g, eeb3, nullptr, e + (size_t)off * DD, 1); }
    }

    // ---- L message-passing layers ----
    for (int l = 0; l < LL; ++l) {
        const float* ew1  = eW1 + (size_t)l * 4 * DD * HH;  const float* eb1l = eb1 + (size_t)l * HH;
        const float* ew2  = eW2 + (size_t)l * HH * HH;      const float* eb2l = eb2 + (size_t)l * HH;
        const float* ew3  = eW3 + (size_t)l * HH * DD;      const float* eb3l = eb3 + (size_t)l * DD;
        const float* nw1  = nW1 + (size_t)l * 4 * DD * HH;  const float* nb1l = nb1 + (size_t)l * HH;
        const float* nw2  = nW2 + (size_t)l * HH * HH;      const float* nb2l = nb2 + (size_t)l * HH;
        const float* nw3  = nW3 + (size_t)l * HH * DD;      const float* nb3l = nb3 + (size_t)l * DD;
        const float* gw1  = gW1 + (size_t)l * 3 * DD * HH;  const float* gb1l = gb1 + (size_t)l * HH;
        const float* gw2  = gW2 + (size_t)l * HH * HH;      const float* gb2l = gb2 + (size_t)l * HH;
        const float* gw3  = gW3 + (size_t)l * HH * DD;      const float* gb3l = gb3 + (size_t)l * DD;
        const float* pw1  = pW1 + (size_t)l * DD * DD;      const float* pb1l = pb1 + (size_t)l * DD;
        const float* pw2  = pW2 + (size_t)l * DD * 3;       const float* pb2l = pb2 + (size_t)l * 3;

        // convert this layer's weights (transposed, hi/lo) — one launch
        wreset();
        bf16* cew1 = wadd(ew1, HH, 4 * DD, 4 * DD);   // [512][1024]
        bf16* cew2 = wadd(ew2, HH, HH, HH);
        bf16* cew3 = wadd(ew3, DD, HH, HH);
        bf16* cnw1 = wadd(nw1, HH, 4 * DD, 4 * DD);
        bf16* cnw2 = wadd(nw2, HH, HH, HH);
        bf16* cnw3 = wadd(nw3, DD, HH, HH);
        bf16* cgw1 = wadd(gw1, HH, 3 * DD, 3 * DD);   // [512][768]
        bf16* cgw2 = wadd(gw2, HH, HH, HH);
        bf16* cgw3 = wadd(gw3, DD, HH, HH);
        bf16* cpw1 = wadd(pw1, DD, DD, DD);
        wflush();
        bf16* lew1 = wlo_of(cew1, HH, 4 * DD);
        bf16* lnw1 = wlo_of(cnw1, HH, 4 * DD);
        bf16* lgw1 = wlo_of(cgw1, HH, 3 * DD);

        // ---- edge update: e += MLP3(concat[e, x[src], x[dst], u[eb]]) ----
        for (int off = 0; off < N_EDGES; off += EC) {
            int cnt = (N_EDGES - off) < EC ? (N_EDGES - off) : EC;
            { GMArgs g = gm_new(cnt, HH);
              gm_part(g, e + (size_t)off * DD, DD, nullptr,    cew1,            lew1,            4 * DD, DD);
              gm_part(g, x,                    DD, src + off,  cew1 + 1 * DD,   lew1 + 1 * DD,   4 * DD, DD);
              gm_part(g, x,                    DD, dst + off,  cew1 + 2 * DD,   lew1 + 2 * DD,   4 * DD, DD);
              gm_part(g, u,                    DD, ebat + off, cew1 + 3 * DD,   lew1 + 3 * DD,   4 * DD, DD);
              gm_run(stream, g, eb1l, nullptr, h1, 1); }
            { GMArgs g = gm_new(cnt, HH); gm_part(g, h1, HH, nullptr, cew2, wlo_of(cew2, HH, HH), HH, HH);
              gm_run(stream, g, eb2l, nullptr, h2, 1); }
            { GMArgs g = gm_new(cnt, DD); gm_part(g, h2, HH, nullptr, cew3, wlo_of(cew3, DD, HH), HH, HH);
              gm_run(stream, g, eb3l, e + (size_t)off * DD, e + (size_t)off * DD, 1); }
        }

        // ---- node update ----
        seg_sum_csr<<<(N_NODES + 3) / 4, 256, 0, stream>>>(e, off_s, idx_s, sent);
        seg_sum_csr<<<(N_NODES + 3) / 4, 256, 0, stream>>>(e, off_d, idx_d, recv);
        for (int off = 0; off < N_NODES; off += NC) {
            int cnt = (N_NODES - off) < NC ? (N_NODES - off) : NC;
            { GMArgs g = gm_new(cnt, HH);
              gm_part(g, x    + (size_t)off * DD, DD, nullptr,          cnw1,          lnw1,          4 * DD, DD);
              gm_part(g, sent + (size_t)off * DD, DD, nullptr,          cnw1 + 1 * DD, lnw1 + 1 * DD, 4 * DD, DD);
              gm_part(g, recv + (size_t)off * DD, DD, nullptr,          cnw1 + 2 * DD, lnw1 + 2 * DD, 4 * DD, DD);
              gm_part(g, u,                       DD, node_batch + off, cnw1 + 3 * DD, lnw1 + 3 * DD, 4 * DD, DD);
              gm_run(stream, g, nb1l, nullptr, h1, 1); }
            { GMArgs g = gm_new(cnt, HH); gm_part(g, h1, HH, nullptr, cnw2, wlo_of(cnw2, HH, HH), HH, HH);
              gm_run(stream, g, nb2l, nullptr, h2, 1); }
            { GMArgs g = gm_new(cnt, DD); gm_part(g, h2, HH, nullptr, cnw3, wlo_of(cnw3, DD, HH), HH, HH);
              gm_run(stream, g, nb3l, x + (size_t)off * DD, x + (size_t)off * DD, 1); }
        }

        // ---- global update (ge == range-sum of `sent`) ----
        range_sum<<<(N_GRAPH + 3) / 4, 256, 0, stream>>>(x, gstart, gn);
        range_sum<<<(N_GRAPH + 3) / 4, 256, 0, stream>>>(sent, gstart, ge);
        { GMArgs g = gm_new(N_GRAPH, HH);
          gm_part(g, u,  DD, nullptr, cgw1,          lgw1,          3 * DD, DD);
          gm_part(g, gn, DD, nullptr, cgw1 + 1 * DD, lgw1 + 1 * DD, 3 * DD, DD);
          gm_part(g, ge, DD, nullptr, cgw1 + 2 * DD, lgw1 + 2 * DD, 3 * DD, DD);
          gm_run(stream, g, gb1l, nullptr, gh1, 1); }
        { GMArgs g = gm_new(N_GRAPH, HH); gm_part(g, gh1, HH, nullptr, cgw2, wlo_of(cgw2, HH, HH), HH, HH);
          gm_run(stream, g, gb2l, nullptr, gh2, 1); }
        { GMArgs g = gm_new(N_GRAPH, DD); gm_part(g, gh2, HH, nullptr, cgw3, wlo_of(cgw3, DD, HH), HH, HH);
          gm_run(stream, g, gb3l, u, u, 1); }

        // ---- position head (h1 reused as [cnt][DD]) ----
        for (int off = 0; off < N_NODES; off += NC) {
            int cnt = (N_NODES - off) < NC ? (N_NODES - off) : NC;
            { GMArgs g = gm_new(cnt, DD); gm_part(g, x + (size_t)off * DD, DD, nullptr, cpw1, wlo_of(cpw1, DD, DD), DD, DD);
              gm_run(stream, g, pb1l, nullptr, h1, 1); }
            pos_head2<<<((size_t)cnt * 64 + 255) / 256, 256, 0, stream>>>(
                h1, pw2, pb2l, pos + (size_t)off * 3, cnt, l == 0 ? 1 : 0);
        }
    }
}